// Round 4
// baseline (479.589 us; speedup 1.0000x reference)
//
#include <hip/hip_runtime.h>
#include <hip/hip_bf16.h>
#include <cstdint>
#include <cstddef>

typedef unsigned short u16;
typedef __attribute__((ext_vector_type(8))) short short8;     // 8 bf16 in 4 VGPRs
typedef __attribute__((ext_vector_type(4))) float floatx4;    // MFMA C/D frag

#define MFMA16(a, b, c) __builtin_amdgcn_mfma_f32_16x16x32_bf16((a), (b), (c), 0, 0, 0)

__device__ __forceinline__ float bf2f(u16 h) {
    unsigned int u = ((unsigned int)h) << 16;
    return __uint_as_float(u);
}
__device__ __forceinline__ u16 f2bf(float f) {
    unsigned int u = __float_as_uint(f);
    u += 0x7fffu + ((u >> 16) & 1u);   // round-to-nearest-even
    return (u16)(u >> 16);
}

// Load 8 consecutive elements (element index `elem`) as bf16, converting from
// f32 if isf32. dst must be 16B-aligned.
__device__ __forceinline__ void load8_cvt(const void* base, size_t elem, int isf32, u16* dst) {
    if (isf32) {
        const float* f = (const float*)base + elem;
        float4 a = *(const float4*)f;
        float4 b = *(const float4*)(f + 4);
        dst[0] = f2bf(a.x); dst[1] = f2bf(a.y); dst[2] = f2bf(a.z); dst[3] = f2bf(a.w);
        dst[4] = f2bf(b.x); dst[5] = f2bf(b.y); dst[6] = f2bf(b.z); dst[7] = f2bf(b.w);
    } else {
        *(uint4*)dst = *(const uint4*)((const u16*)base + elem);
    }
}

// ---------------------------------------------------------------------------
// Probes.
// flags[0]: mask is byte-bool (1) vs 4-byte (int32/f32) (0).
//   nonzero words in first 4096 words: byte mask ~1409 (1-0.9^4), 4-byte ~410.
// flags[1]: inputs are f32 (1) vs bf16 (0).
//   even-index u16 of query: bf16 data -> ~100% have exp field <= 133;
//   f32 low-mantissa halves -> uniform -> ~52%.
// ---------------------------------------------------------------------------
__global__ void probe_kernel(const uint32_t* __restrict__ mask,
                             const u16* __restrict__ q,
                             int* __restrict__ flags) {
    __shared__ int cntm, cntd;
    if (threadIdx.x == 0) { cntm = 0; cntd = 0; }
    __syncthreads();
    int cm = 0, cd = 0;
    for (int i = threadIdx.x; i < 4096; i += 256) cm += (mask[i] != 0u) ? 1 : 0;
    for (int i = threadIdx.x; i < 1024; i += 256) {
        u16 v = q[2 * i];
        int ex = (v >> 7) & 0xFF;
        if (ex <= 133) cd++;
    }
    atomicAdd(&cntm, cm);
    atomicAdd(&cntd, cd);
    __syncthreads();
    if (threadIdx.x == 0) {
        flags[0] = (cntm > 900) ? 1 : 0;   // byte mask
        flags[1] = (cntd > 820) ? 0 : 1;   // f32 inputs
    }
}

// ---------------------------------------------------------------------------
// C = A(4096 x 1024) @ W + bias.  A row-major, W row-major [K][N].
// User tensors' dtype per flags[1]; internal tensors always bf16.
// 128x128 tile, BK=32, 4 waves each 64x64.  W tile transposed into LDS.
// headSplit=1: out[((b*16 + n/64)*1024 + t)*64 + n%64]  (b=m>>10, t=m&1023)
// headSplit=0: out[m*1024 + n]
// ---------------------------------------------------------------------------
struct GemmArgs {
    const void* A[3];
    const void* W[3];
    const void* bias[3];
    void* out[3];
    int headSplit;
    int aUser;     // A is a user tensor (dtype per flag) else bf16 internal
    int outUser;   // out is d_out (dtype per flag) else bf16 internal
    const int* flags;
};

__global__ __launch_bounds__(256) void gemm_kernel(GemmArgs args) {
    const int K = 1024;
    const int z = blockIdx.z;
    const void* A    = args.A[z];
    const void* W    = args.W[z];
    const void* bias = args.bias[z];
    void* out        = args.out[z];

    const int f32m  = args.flags[1];
    const int aF32   = args.aUser ? f32m : 0;
    const int outF32 = args.outUser ? f32m : 0;

    const int n0 = blockIdx.x * 128;
    const int m0 = blockIdx.y * 128;
    const int tid  = threadIdx.x;
    const int lane = tid & 63;
    const int wave = tid >> 6;
    const int wm = wave >> 1, wn = wave & 1;   // 2x2 wave grid, 64x64 each
    const int l15 = lane & 15, quad = lane >> 4;

    __shared__ __align__(16) u16 lds_a[128 * 40];   // [m][k], pitch 40 (+8 pad)
    __shared__ __align__(16) u16 lds_b[128 * 40];   // [n][k], pitch 40

    floatx4 acc[4][4];
#pragma unroll
    for (int i = 0; i < 4; i++)
#pragma unroll
        for (int j = 0; j < 4; j++) acc[i][j] = (floatx4){0.f, 0.f, 0.f, 0.f};

    const int kr2 = (tid >> 4) * 2;      // even k-row pair base, 0..30
    const int nc  = (tid & 15) * 8;      // n chunk, 0..120

    for (int k0 = 0; k0 < K; k0 += 32) {
        __syncthreads();   // previous iteration's fragment reads done
        // A tile: 128 rows x 32 k, natural layout
#pragma unroll
        for (int it = 0; it < 2; it++) {
            int o = tid + it * 256;          // 512 octs
            int row = o >> 2, oc = o & 3;
            u16 tmp[8] __attribute__((aligned(16)));
            load8_cvt(A, (size_t)(m0 + row) * K + k0 + oc * 8, aF32, tmp);
            *(uint4*)(lds_a + row * 40 + oc * 8) = *(const uint4*)tmp;
        }
        // W tile rows k0+kr2, k0+kr2+1, cols n0+nc..+7 -> lds_b[n][k]
        {
            u16 ta[8] __attribute__((aligned(16)));
            u16 tb[8] __attribute__((aligned(16)));
            load8_cvt(W, (size_t)(k0 + kr2) * 1024 + n0 + nc, f32m, ta);
            load8_cvt(W, (size_t)(k0 + kr2 + 1) * 1024 + n0 + nc, f32m, tb);
#pragma unroll
            for (int j = 0; j < 8; j++) {
                uint32_t pack = (uint32_t)ta[j] | ((uint32_t)tb[j] << 16);
                *(uint32_t*)(lds_b + (size_t)(nc + j) * 40 + kr2) = pack;
            }
        }
        __syncthreads();

        short8 af[4], bfr[4];
#pragma unroll
        for (int i = 0; i < 4; i++) {
            af[i]  = *(const short8*)(lds_a + (wm * 64 + i * 16 + l15) * 40 + quad * 8);
            bfr[i] = *(const short8*)(lds_b + (wn * 64 + i * 16 + l15) * 40 + quad * 8);
        }
#pragma unroll
        for (int i = 0; i < 4; i++)
#pragma unroll
            for (int j = 0; j < 4; j++) acc[i][j] = MFMA16(af[i], bfr[j], acc[i][j]);
    }

    // epilogue: bias + store.  C/D layout: col = lane&15, row = quad*4 + r
#pragma unroll
    for (int j = 0; j < 4; j++) {
        int n = n0 + wn * 64 + j * 16 + l15;
        float bv = f32m ? ((const float*)bias)[n] : bf2f(((const u16*)bias)[n]);
#pragma unroll
        for (int i = 0; i < 4; i++) {
#pragma unroll
            for (int r = 0; r < 4; r++) {
                int m = m0 + wm * 64 + i * 16 + quad * 4 + r;
                float v = acc[i][j][r] + bv;
                size_t addr;
                if (args.headSplit) {
                    int bb = m >> 10, t = m & 1023;
                    addr = ((size_t)(bb * 16 + (n >> 6)) << 16) + (size_t)t * 64 + (n & 63);
                } else {
                    addr = (size_t)m * 1024 + n;
                }
                if (outF32) ((float*)out)[addr] = v;
                else        ((u16*)out)[addr]   = f2bf(v);
            }
        }
    }
}

// ---------------------------------------------------------------------------
// Flash attention: one block = 64 q-rows of one (b,h).  4 waves x 16 rows.
// Q,K,V: (b,h,t,64) bf16 internal.  V tile LDS-transposed to [d][t2].
// mask: byte or 4-byte per flags[0] (nonzero = masked).  X: (b,t,1024) bf16.
// ---------------------------------------------------------------------------
__global__ __launch_bounds__(256) void attn_kernel(const u16* __restrict__ Q,
                                                   const u16* __restrict__ Kh,
                                                   const u16* __restrict__ Vh,
                                                   const void* __restrict__ mask,
                                                   const int* __restrict__ flags,
                                                   u16* __restrict__ X) {
    const int T = 1024;
    const int bh = blockIdx.y;
    const int b = bh >> 4, h = bh & 15;
    const int q0 = blockIdx.x * 64;
    const int tid = threadIdx.x;
    const int lane = tid & 63, wave = tid >> 6;
    const int l15 = lane & 15, quad = lane >> 4;

    const int bytemode = flags[0];
    const uint8_t* m8 = (const uint8_t*)mask;
    const int* m32 = (const int*)mask;

    __shared__ __align__(16) u16 lds_k[64 * 72];      // [t2][d] (+pad)
    __shared__ __align__(16) u16 lds_v[64 * 72];      // [d][t2] (+pad)
    __shared__ __align__(16) u16 lds_p[4][16 * 72];   // per-wave P staging

    const size_t headoff = (size_t)bh << 16;   // * 1024 * 64

    // Q fragments (A-operand): row = lane&15, k = quad*8 + j (+32 for ks=1)
    short8 aq[2];
    {
        int qrow = q0 + wave * 16 + l15;
        const u16* qp = Q + headoff + (size_t)qrow * 64 + quad * 8;
        aq[0] = *(const short8*)(qp);
        aq[1] = *(const short8*)(qp + 32);
    }

    floatx4 O[4];
#pragma unroll
    for (int i = 0; i < 4; i++) O[i] = (floatx4){0.f, 0.f, 0.f, 0.f};
    float mrow[4], lrow[4];
#pragma unroll
    for (int r = 0; r < 4; r++) { mrow[r] = -1e30f; lrow[r] = 0.f; }

    const int t2s = (tid >> 3) * 2;    // even t2 pair base, 0..62
    const int ds  = (tid & 7) * 8;     // d chunk, 0..56

    for (int j0 = 0; j0 < T; j0 += 64) {
        __syncthreads();   // previous iteration's reads done
        // K tile, natural [t2][d]
#pragma unroll
        for (int it = 0; it < 2; it++) {
            int o = tid + it * 256;
            int row = o >> 3, oc = o & 7;
            uint4 vk = *(const uint4*)(Kh + headoff + (size_t)(j0 + row) * 64 + oc * 8);
            *(uint4*)(lds_k + row * 72 + oc * 8) = vk;
        }
        // V tile, transposed to [d][t2]
        {
            uint4 va = *(const uint4*)(Vh + headoff + (size_t)(j0 + t2s) * 64 + ds);
            uint4 vb = *(const uint4*)(Vh + headoff + (size_t)(j0 + t2s + 1) * 64 + ds);
            const u16* pa = (const u16*)&va;
            const u16* pb = (const u16*)&vb;
#pragma unroll
            for (int j = 0; j < 8; j++) {
                uint32_t pack = (uint32_t)pa[j] | ((uint32_t)pb[j] << 16);
                *(uint32_t*)(lds_v + (size_t)(ds + j) * 72 + t2s) = pack;
            }
        }
        __syncthreads();

        // S = Q K^T (per wave: 16 q-rows x 64 t2)
        floatx4 s[4];
#pragma unroll
        for (int nt = 0; nt < 4; nt++) s[nt] = (floatx4){0.f, 0.f, 0.f, 0.f};
#pragma unroll
        for (int ks = 0; ks < 2; ks++) {
#pragma unroll
            for (int nt = 0; nt < 4; nt++) {
                short8 bk = *(const short8*)(lds_k + (nt * 16 + l15) * 72 + ks * 32 + quad * 8);
                s[nt] = MFMA16(aq[ks], bk, s[nt]);
            }
        }

        // scale 1/sqrt(64) + mask -> -inf
        const int qbase = q0 + wave * 16 + quad * 4;
#pragma unroll
        for (int nt = 0; nt < 4; nt++) {
            int t2 = j0 + nt * 16 + l15;
#pragma unroll
            for (int r = 0; r < 4; r++) {
                int q = qbase + r;
                size_t midx = (size_t)(b * 1024 + q) * 1024 + t2;
                int mv = bytemode ? (int)m8[midx] : m32[midx];
                float v = s[nt][r] * 0.125f;
                s[nt][r] = mv ? -INFINITY : v;
            }
        }

        // online softmax (row = quad*4 + r; reduce across the 16 l15 lanes)
#pragma unroll
        for (int r = 0; r < 4; r++) {
            float mx = fmaxf(fmaxf(s[0][r], s[1][r]), fmaxf(s[2][r], s[3][r]));
#pragma unroll
            for (int off = 1; off < 16; off <<= 1) mx = fmaxf(mx, __shfl_xor(mx, off, 64));
            float mnew = fmaxf(mrow[r], mx);
            float alpha = __expf(mrow[r] - mnew);
            mrow[r] = mnew;
            float sum = 0.f;
#pragma unroll
            for (int nt = 0; nt < 4; nt++) {
                float p = __expf(s[nt][r] - mnew);   // masked: exp(-inf) = 0
                s[nt][r] = p;
                sum += p;
            }
#pragma unroll
            for (int off = 1; off < 16; off <<= 1) sum += __shfl_xor(sum, off, 64);
            lrow[r] = lrow[r] * alpha + sum;
#pragma unroll
            for (int dt = 0; dt < 4; dt++) O[dt][r] *= alpha;
        }

        // P (C-layout) -> LDS -> A-operand layout
        u16* pl = lds_p[wave];
#pragma unroll
        for (int nt = 0; nt < 4; nt++)
#pragma unroll
            for (int r = 0; r < 4; r++)
                pl[(quad * 4 + r) * 72 + nt * 16 + l15] = f2bf(s[nt][r]);
        __syncthreads();

        // O += P @ V  (B-operand from [d][t2] tile: n=d, k=t2 contiguous)
#pragma unroll
        for (int ks = 0; ks < 2; ks++) {
            short8 af = *(const short8*)(pl + l15 * 72 + ks * 32 + quad * 8);
#pragma unroll
            for (int dt = 0; dt < 4; dt++) {
                short8 bv = *(const short8*)(lds_v + (dt * 16 + l15) * 72 + ks * 32 + quad * 8);
                O[dt] = MFMA16(af, bv, O[dt]);
            }
        }
    }

    // epilogue: O / l, write X (b, t, h*64 + d).
    // lrow==0 (fully-masked row) -> 0, matching reference's where(m,0,attn).
#pragma unroll
    for (int r = 0; r < 4; r++) {
        int q = q0 + wave * 16 + quad * 4 + r;
        float inv = (lrow[r] > 0.f) ? (1.f / lrow[r]) : 0.f;
#pragma unroll
        for (int dt = 0; dt < 4; dt++) {
            int d = dt * 16 + l15;
            X[(size_t)(b * 1024 + q) * 1024 + h * 64 + d] = f2bf(O[dt][r] * inv);
        }
    }
}

// ---------------------------------------------------------------------------
extern "C" void kernel_launch(void* const* d_in, const int* in_sizes, int n_in,
                              void* d_out, int out_size, void* d_ws, size_t ws_size,
                              hipStream_t stream) {
    const void* query = d_in[0];
    const void* key   = d_in[1];
    const void* value = d_in[2];
    const void* mask  = d_in[3];
    const void* Wq = d_in[4];
    const void* bq = d_in[5];
    const void* Wk = d_in[6];
    const void* bk = d_in[7];
    const void* Wv = d_in[8];
    const void* bv = d_in[9];
    const void* Wo = d_in[10];
    const void* bo = d_in[11];

    // Workspace layout (24 MB + 128 B):
    //   [0,128)            flags
    //   [128, 8M+128)      Kh (b,h,t,d) bf16
    //   [8M+128, 16M+128)  Vh (b,h,t,d) bf16
    //   [16M+128, 24M+128) X  (b,t,1024) bf16
    // Qh (bf16) lives in d_out; consumed by attn before final GEMM overwrites.
    char* wsb = (char*)d_ws;
    int* flags = (int*)wsb;
    u16* Kh = (u16*)(wsb + 128);
    u16* Vh = (u16*)(wsb + 128 + (8u << 20));
    u16* X  = (u16*)(wsb + 128 + (16u << 20));
    u16* Qh = (u16*)d_out;

    probe_kernel<<<1, 256, 0, stream>>>((const uint32_t*)mask, (const u16*)query, flags);
    {   // QKV projections, head-split layout
        GemmArgs ga{};
        ga.A[0] = query; ga.A[1] = key; ga.A[2] = value;
        ga.W[0] = Wq; ga.W[1] = Wk; ga.W[2] = Wv;
        ga.bias[0] = bq; ga.bias[1] = bk; ga.bias[2] = bv;
        ga.out[0] = Qh; ga.out[1] = Kh; ga.out[2] = Vh;
        ga.headSplit = 1; ga.aUser = 1; ga.outUser = 0; ga.flags = flags;
        gemm_kernel<<<dim3(8, 32, 3), dim3(256), 0, stream>>>(ga);
    }
    attn_kernel<<<dim3(16, 64), dim3(256), 0, stream>>>(Qh, Kh, Vh, mask, flags, X);
    {   // output projection
        GemmArgs ga{};
        ga.A[0] = X; ga.W[0] = Wo; ga.bias[0] = bo;
        ga.out[0] = d_out;
        ga.headSplit = 0; ga.aUser = 0; ga.outUser = 1; ga.flags = flags;
        gemm_kernel<<<dim3(8, 32, 1), dim3(256), 0, stream>>>(ga);
    }
}

// Round 5
// 281.464 us; speedup vs baseline: 1.7039x; 1.7039x over previous
//
#include <hip/hip_runtime.h>
#include <cstdint>
#include <cstddef>

typedef unsigned short u16;
typedef __attribute__((ext_vector_type(8))) short short8;     // 8 bf16 in 4 VGPRs
typedef __attribute__((ext_vector_type(4))) float floatx4;    // MFMA C/D frag

#define MFMA16(a, b, c) __builtin_amdgcn_mfma_f32_16x16x32_bf16((a), (b), (c), 0, 0, 0)

__device__ __forceinline__ u16 f2bf(float f) {
    unsigned int u = __float_as_uint(f);
    u += 0x7fffu + ((u >> 16) & 1u);   // round-to-nearest-even
    return (u16)(u >> 16);
}

typedef const __attribute__((address_space(1))) void gvoid;
typedef __attribute__((address_space(3))) void lvoid;
__device__ __forceinline__ void gload_lds16(const u16* g, u16* l) {
    __builtin_amdgcn_global_load_lds((gvoid*)g, (lvoid*)l, 16, 0, 0);
}

// ---------------------------------------------------------------------------
// Convert+transpose weights: W f32 [k][n] -> Wt bf16 [n][k].  64x64 tiles.
// ---------------------------------------------------------------------------
struct CvtTArgs { const float* src[4]; u16* dst[4]; };

__global__ __launch_bounds__(256) void cvtT_kernel(CvtTArgs a) {
    const float* src = a.src[blockIdx.z];
    u16* dst         = a.dst[blockIdx.z];
    const int c0 = blockIdx.x * 64;
    const int r0 = blockIdx.y * 64;
    const int tid = threadIdx.x;

    __shared__ __align__(16) u16 lds[64 * 72];   // +8 pad

#pragma unroll
    for (int it = 0; it < 2; it++) {
        int o = tid + it * 256;            // 512 chunks of 8
        int row = o >> 3, c8 = o & 7;
        const float* p = src + (size_t)(r0 + row) * 1024 + c0 + c8 * 8;
        float4 v0 = *(const float4*)p;
        float4 v1 = *(const float4*)(p + 4);
        u16 t[8] __attribute__((aligned(16)));
        t[0] = f2bf(v0.x); t[1] = f2bf(v0.y); t[2] = f2bf(v0.z); t[3] = f2bf(v0.w);
        t[4] = f2bf(v1.x); t[5] = f2bf(v1.y); t[6] = f2bf(v1.z); t[7] = f2bf(v1.w);
        *(uint4*)(lds + row * 72 + c8 * 8) = *(const uint4*)t;
    }
    __syncthreads();
#pragma unroll
    for (int it = 0; it < 2; it++) {
        int o = tid + it * 256;
        int i = o >> 3, j8 = o & 7;        // dst row i (= src col c0+i)
        u16 t[8] __attribute__((aligned(16)));
#pragma unroll
        for (int j = 0; j < 8; j++) t[j] = lds[(j8 * 8 + j) * 72 + i];
        *(uint4*)(dst + (size_t)(c0 + i) * 1024 + r0 + j8 * 8) = *(const uint4*)t;
    }
}

// ---------------------------------------------------------------------------
// GEMM: C = scale * (A(4096x1024) @ Wt^T + bias).  Wt bf16 [N][K] (pre-T).
// m97 structure: unpadded LDS [128][32], global_load_lds width-16 for bf16
// operands, ds_read_b128 fragments, 16 MFMA per K-step per wave.
// A_F32=1: A is user f32, staged via float4+cvt.  A_F32=0: A bf16, async DMA.
// OUT_MODE=0: bf16 head-split out[((b*16+n/64)*1024+t)*64 + n%64]
// OUT_MODE=1: f32 out[m*1024+n]
// ---------------------------------------------------------------------------
struct GemmArgs {
    const void* A[3];
    const u16* Wt[3];
    const float* bias[3];
    void* out[3];
    float scale[3];
};

template<int A_F32, int OUT_MODE>
__global__ __launch_bounds__(256) void gemm_kernel(GemmArgs args) {
    const int K = 1024;
    const int z = blockIdx.z;
    const void* Aptr  = args.A[z];
    const u16* Wt     = args.Wt[z];
    const float* bias = args.bias[z];
    void* outp        = args.out[z];
    const float scale = args.scale[z];

    const int n0 = blockIdx.x * 128;
    const int m0 = blockIdx.y * 128;
    const int tid  = threadIdx.x;
    const int lane = tid & 63;
    const int wave = tid >> 6;
    const int wm = wave >> 1, wn = wave & 1;   // 2x2 wave grid, 64x64 each
    const int l15 = lane & 15, quad = lane >> 4;

    __shared__ __align__(16) u16 lds_a[128 * 32];   // [m][k], unpadded (DMA layout)
    __shared__ __align__(16) u16 lds_b[128 * 32];   // [n][k], unpadded

    floatx4 acc[4][4];
#pragma unroll
    for (int i = 0; i < 4; i++)
#pragma unroll
        for (int j = 0; j < 4; j++) acc[i][j] = (floatx4){0.f, 0.f, 0.f, 0.f};

    const int drow = lane >> 2;          // 0..15: row within 16-row DMA group
    const int dcol = (lane & 3) * 8;     // 0/8/16/24: k-chunk

    for (int k0 = 0; k0 < K; k0 += 32) {
        __syncthreads();   // previous iteration's fragment reads done
        // B tile: wave w stages rows [w*32, w*32+32) via async DMA
#pragma unroll
        for (int i = 0; i < 2; i++) {
            int rbase = wave * 32 + i * 16;
            gload_lds16(Wt + (size_t)(n0 + rbase + drow) * K + k0 + dcol,
                        lds_b + rbase * 32);
        }
        // A tile
        if (A_F32) {
            const float* Af = (const float*)Aptr;
#pragma unroll
            for (int it = 0; it < 2; it++) {
                int o = tid + it * 256;          // 512 chunks of 8
                int row = o >> 2, c8 = o & 3;
                const float* p = Af + (size_t)(m0 + row) * K + k0 + c8 * 8;
                float4 v0 = *(const float4*)p;
                float4 v1 = *(const float4*)(p + 4);
                u16 t[8] __attribute__((aligned(16)));
                t[0] = f2bf(v0.x); t[1] = f2bf(v0.y); t[2] = f2bf(v0.z); t[3] = f2bf(v0.w);
                t[4] = f2bf(v1.x); t[5] = f2bf(v1.y); t[6] = f2bf(v1.z); t[7] = f2bf(v1.w);
                *(uint4*)(lds_a + row * 32 + c8 * 8) = *(const uint4*)t;
            }
        } else {
            const u16* Ab = (const u16*)Aptr;
#pragma unroll
            for (int i = 0; i < 2; i++) {
                int rbase = wave * 32 + i * 16;
                gload_lds16(Ab + (size_t)(m0 + rbase + drow) * K + k0 + dcol,
                            lds_a + rbase * 32);
            }
        }
        __syncthreads();   // waits vmcnt(0)+lgkmcnt(0): DMA + ds_writes visible

        short8 af[4], bf[4];
#pragma unroll
        for (int i = 0; i < 4; i++) {
            af[i] = *(const short8*)(lds_a + (wm * 64 + i * 16 + l15) * 32 + quad * 8);
            bf[i] = *(const short8*)(lds_b + (wn * 64 + i * 16 + l15) * 32 + quad * 8);
        }
#pragma unroll
        for (int i = 0; i < 4; i++)
#pragma unroll
            for (int j = 0; j < 4; j++) acc[i][j] = MFMA16(af[i], bf[j], acc[i][j]);
    }

    // epilogue.  C/D layout: col = lane&15, row = quad*4 + r
#pragma unroll
    for (int j = 0; j < 4; j++) {
        int n = n0 + wn * 64 + j * 16 + l15;
        float bv = bias[n];
#pragma unroll
        for (int i = 0; i < 4; i++) {
#pragma unroll
            for (int r = 0; r < 4; r++) {
                int m = m0 + wm * 64 + i * 16 + quad * 4 + r;
                float v = (acc[i][j][r] + bv) * scale;
                if (OUT_MODE == 0) {
                    int bb = m >> 10, t = m & 1023;
                    size_t addr = ((size_t)(bb * 16 + (n >> 6)) << 16) + (size_t)t * 64 + (n & 63);
                    ((u16*)outp)[addr] = f2bf(v);
                } else {
                    ((float*)outp)[(size_t)m * 1024 + n] = v;
                }
            }
        }
    }
}

// ---------------------------------------------------------------------------
// Flash attention: one block = 64 q-rows of one (b,h).  4 waves x 16 rows.
// Q,K,V: (b,h,t,64) bf16 (1/8 scale pre-folded into Q).  V tile LDS-transposed
// to [d][t2].  mask int32 (nonzero = masked).  X out: (b,t,1024) bf16.
// ---------------------------------------------------------------------------
__global__ __launch_bounds__(256) void attn_kernel(const u16* __restrict__ Q,
                                                   const u16* __restrict__ Kh,
                                                   const u16* __restrict__ Vh,
                                                   const int* __restrict__ mask,
                                                   u16* __restrict__ X) {
    const int T = 1024;
    const int bh = blockIdx.y;
    const int b = bh >> 4, h = bh & 15;
    const int q0 = blockIdx.x * 64;
    const int tid = threadIdx.x;
    const int lane = tid & 63, wave = tid >> 6;
    const int l15 = lane & 15, quad = lane >> 4;

    __shared__ __align__(16) u16 lds_k[64 * 72];      // [t2][d] (+pad)
    __shared__ __align__(16) u16 lds_v[64 * 72];      // [d][t2] (+pad)
    __shared__ __align__(16) u16 lds_p[4][16 * 72];   // per-wave P staging

    const size_t headoff = (size_t)bh << 16;   // * 1024 * 64

    // Q fragments (A-operand): row = lane&15, k = quad*8 + j (+32 for ks=1)
    short8 aq[2];
    {
        int qrow = q0 + wave * 16 + l15;
        const u16* qp = Q + headoff + (size_t)qrow * 64 + quad * 8;
        aq[0] = *(const short8*)(qp);
        aq[1] = *(const short8*)(qp + 32);
    }

    floatx4 O[4];
#pragma unroll
    for (int i = 0; i < 4; i++) O[i] = (floatx4){0.f, 0.f, 0.f, 0.f};
    float mrow[4], lrow[4];
#pragma unroll
    for (int r = 0; r < 4; r++) { mrow[r] = -1e30f; lrow[r] = 0.f; }

    const int t2s = (tid >> 3) * 2;    // even t2 pair base, 0..62
    const int ds  = (tid & 7) * 8;     // d chunk, 0..56

    for (int j0 = 0; j0 < T; j0 += 64) {
        __syncthreads();   // previous iteration's reads done
        // K tile, natural [t2][d]
#pragma unroll
        for (int it = 0; it < 2; it++) {
            int o = tid + it * 256;
            int row = o >> 3, oc = o & 7;
            uint4 vk = *(const uint4*)(Kh + headoff + (size_t)(j0 + row) * 64 + oc * 8);
            *(uint4*)(lds_k + row * 72 + oc * 8) = vk;
        }
        // V tile, transposed to [d][t2]
        {
            uint4 va = *(const uint4*)(Vh + headoff + (size_t)(j0 + t2s) * 64 + ds);
            uint4 vb = *(const uint4*)(Vh + headoff + (size_t)(j0 + t2s + 1) * 64 + ds);
            const u16* pa = (const u16*)&va;
            const u16* pb = (const u16*)&vb;
#pragma unroll
            for (int j = 0; j < 8; j++) {
                uint32_t pack = (uint32_t)pa[j] | ((uint32_t)pb[j] << 16);
                *(uint32_t*)(lds_v + (size_t)(ds + j) * 72 + t2s) = pack;
            }
        }
        __syncthreads();

        // S = Q K^T (per wave: 16 q-rows x 64 t2); 1/8 scale already in Q
        floatx4 s[4];
#pragma unroll
        for (int nt = 0; nt < 4; nt++) s[nt] = (floatx4){0.f, 0.f, 0.f, 0.f};
#pragma unroll
        for (int ks = 0; ks < 2; ks++) {
#pragma unroll
            for (int nt = 0; nt < 4; nt++) {
                short8 bk = *(const short8*)(lds_k + (nt * 16 + l15) * 72 + ks * 32 + quad * 8);
                s[nt] = MFMA16(aq[ks], bk, s[nt]);
            }
        }

        // mask -> -inf
        const int qbase = q0 + wave * 16 + quad * 4;
#pragma unroll
        for (int nt = 0; nt < 4; nt++) {
            int t2 = j0 + nt * 16 + l15;
#pragma unroll
            for (int r = 0; r < 4; r++) {
                int q = qbase + r;
                int mv = mask[(size_t)(b * 1024 + q) * 1024 + t2];
                s[nt][r] = mv ? -INFINITY : s[nt][r];
            }
        }

        // online softmax (row = quad*4 + r; reduce across the 16 l15 lanes)
#pragma unroll
        for (int r = 0; r < 4; r++) {
            float mx = fmaxf(fmaxf(s[0][r], s[1][r]), fmaxf(s[2][r], s[3][r]));
#pragma unroll
            for (int off = 1; off < 16; off <<= 1) mx = fmaxf(mx, __shfl_xor(mx, off, 64));
            float mnew = fmaxf(mrow[r], mx);
            float alpha = __expf(mrow[r] - mnew);
            mrow[r] = mnew;
            float sum = 0.f;
#pragma unroll
            for (int nt = 0; nt < 4; nt++) {
                float p = __expf(s[nt][r] - mnew);   // masked: exp(-inf) = 0
                s[nt][r] = p;
                sum += p;
            }
#pragma unroll
            for (int off = 1; off < 16; off <<= 1) sum += __shfl_xor(sum, off, 64);
            lrow[r] = lrow[r] * alpha + sum;
#pragma unroll
            for (int dt = 0; dt < 4; dt++) O[dt][r] *= alpha;
        }

        // P (C-layout) -> LDS -> A-operand layout
        u16* pl = lds_p[wave];
#pragma unroll
        for (int nt = 0; nt < 4; nt++)
#pragma unroll
            for (int r = 0; r < 4; r++)
                pl[(quad * 4 + r) * 72 + nt * 16 + l15] = f2bf(s[nt][r]);
        __syncthreads();

        // O += P @ V  (B-operand from [d][t2] tile: n=d, k=t2 contiguous)
#pragma unroll
        for (int ks = 0; ks < 2; ks++) {
            short8 af = *(const short8*)(pl + l15 * 72 + ks * 32 + quad * 8);
#pragma unroll
            for (int dt = 0; dt < 4; dt++) {
                short8 bv = *(const short8*)(lds_v + (dt * 16 + l15) * 72 + ks * 32 + quad * 8);
                O[dt] = MFMA16(af, bv, O[dt]);
            }
        }
    }

    // epilogue: O / l, write X (b, t, h*64 + d); lrow==0 -> 0 (fully masked)
#pragma unroll
    for (int r = 0; r < 4; r++) {
        int q = q0 + wave * 16 + quad * 4 + r;
        float inv = (lrow[r] > 0.f) ? (1.f / lrow[r]) : 0.f;
#pragma unroll
        for (int dt = 0; dt < 4; dt++) {
            int d = dt * 16 + l15;
            X[(size_t)(b * 1024 + q) * 1024 + h * 64 + d] = f2bf(O[dt][r] * inv);
        }
    }
}

// ---------------------------------------------------------------------------
extern "C" void kernel_launch(void* const* d_in, const int* in_sizes, int n_in,
                              void* d_out, int out_size, void* d_ws, size_t ws_size,
                              hipStream_t stream) {
    const float* query = (const float*)d_in[0];
    const float* key   = (const float*)d_in[1];
    const float* value = (const float*)d_in[2];
    const int*   mask  = (const int*)d_in[3];
    const float* Wq = (const float*)d_in[4];
    const float* bq = (const float*)d_in[5];
    const float* Wk = (const float*)d_in[6];
    const float* bk = (const float*)d_in[7];
    const float* Wv = (const float*)d_in[8];
    const float* bv = (const float*)d_in[9];
    const float* Wo = (const float*)d_in[10];
    const float* bo = (const float*)d_in[11];

    // ws (24 MiB): Wt0..3 (4 x 2 MiB) | Vh (8 MiB) | X (8 MiB)
    // d_out (16 MiB f32): Qh bf16 [0,8M) + Kh bf16 [8M,16M) until out-proj.
    char* wsb = (char*)d_ws;
    u16* Wt0 = (u16*)wsb;
    u16* Wt1 = Wt0 + (1u << 20);
    u16* Wt2 = Wt0 + (2u << 20);
    u16* Wt3 = Wt0 + (3u << 20);
    u16* Vh  = (u16*)(wsb + (8u << 20));
    u16* X   = (u16*)(wsb + (16u << 20));
    u16* Qh  = (u16*)d_out;
    u16* Kh  = (u16*)d_out + (4u << 20);

    {   // convert+transpose all weights
        CvtTArgs ca{};
        ca.src[0] = Wq; ca.src[1] = Wk; ca.src[2] = Wv; ca.src[3] = Wo;
        ca.dst[0] = Wt0; ca.dst[1] = Wt1; ca.dst[2] = Wt2; ca.dst[3] = Wt3;
        cvtT_kernel<<<dim3(16, 16, 4), dim3(256), 0, stream>>>(ca);
    }
    {   // QKV projections (A f32, head-split bf16 out; 1/8 folded into Q)
        GemmArgs ga{};
        ga.A[0] = query; ga.A[1] = key; ga.A[2] = value;
        ga.Wt[0] = Wt0; ga.Wt[1] = Wt1; ga.Wt[2] = Wt2;
        ga.bias[0] = bq; ga.bias[1] = bk; ga.bias[2] = bv;
        ga.out[0] = Qh; ga.out[1] = Kh; ga.out[2] = Vh;
        ga.scale[0] = 0.125f; ga.scale[1] = 1.f; ga.scale[2] = 1.f;
        gemm_kernel<1, 0><<<dim3(8, 32, 3), dim3(256), 0, stream>>>(ga);
    }
    attn_kernel<<<dim3(16, 64), dim3(256), 0, stream>>>(Qh, Kh, Vh, mask, X);
    {   // output projection (A bf16 internal, f32 out to d_out)
        GemmArgs ga{};
        ga.A[0] = X; ga.Wt[0] = Wt3; ga.bias[0] = bo;
        ga.out[0] = d_out; ga.scale[0] = 1.f;
        gemm_kernel<0, 1><<<dim3(8, 32, 1), dim3(256), 0, stream>>>(ga);
    }
}